// Round 15
// baseline (105.127 us; speedup 1.0000x reference)
//
#include <hip/hip_runtime.h>
#include <math.h>

#define EMB 512
#define NM 5
#define HID 64
#define NQ 2048
#define NP 256

typedef __attribute__((ext_vector_type(8))) short short8;   // 8 bf16 = 16B
typedef __attribute__((ext_vector_type(4))) float floatx4;

// ws layout (bytes)
#define A_BY 0u                    // A[m][q][h] f32 (+b1)   2,621,440
#define B_BY 2621440u              // B[m][h/4][p][h%4] f32    327,680

#define LST 72                     // LDS row stride in shorts (144B, 16B-aligned)

__device__ inline unsigned short bfr(float f) {            // f32 -> bf16 RNE
    unsigned u = __float_as_uint(f);
    u += 0x7FFFu + ((u >> 16) & 1u);
    return (unsigned short)(u >> 16);
}

__device__ inline void cvt8(float4 a, float4 b, short8& hi, short8& lo) {
#define C1(I, V) { unsigned short h_ = bfr(V); hi[I] = (short)h_; \
    lo[I] = (short)bfr(V - __uint_as_float(((unsigned)h_) << 16)); }
    C1(0, a.x) C1(1, a.y) C1(2, a.z) C1(3, a.w)
    C1(4, b.x) C1(5, b.y) C1(6, b.z) C1(7, b.w)
#undef C1
}
__device__ inline void cvt8hi(float4 a, float4 b, short8& hi) {
    hi[0] = (short)bfr(a.x); hi[1] = (short)bfr(a.y);
    hi[2] = (short)bfr(a.z); hi[3] = (short)bfr(a.w);
    hi[4] = (short)bfr(b.x); hi[5] = (short)bfr(b.y);
    hi[6] = (short)bfr(b.z); hi[7] = (short)bfr(b.w);
}

// ---------------------------------------------------------------------------
// Kernel 1: LDS double-buffered MFMA GEMM (unchanged from R14 — 92.6 µs best).
__global__ __launch_bounds__(256) void gemm_v3(const float* __restrict__ Q,
                                               const float* __restrict__ P,
                                               const float* __restrict__ W1,
                                               const float* __restrict__ b1,
                                               float* __restrict__ A,
                                               float* __restrict__ Bv) {
    __shared__ short XH[2][16 * LST];
    __shared__ short WH[2][64 * LST];
    __shared__ short WL[2][64 * LST];

    int tid  = threadIdx.x;
    int lane = tid & 63;
    int ht   = tid >> 6;
    int m    = blockIdx.x % 5;
    int rt   = blockIdx.x / 5;           // 0..143
    int r0   = rt * 16;
    bool isQ = rt < 128;

    int wrow = tid >> 3;                 // 0..31  (also rows +32)
    int wg8  = (tid & 7) * 8;            // k offset within 64-chunk
    const float* wb  = W1 + (size_t)m * 64 * 1024 + (isQ ? 0 : EMB);
    const float* wp0 = wb + (size_t)wrow * 1024 + wg8;
    const float* wp1 = wb + (size_t)(wrow + 32) * 1024 + wg8;
    bool hasX = tid < 128;
    int xrow  = tid >> 3;                // 0..15 when hasX
    const float* xp = (isQ ? Q + (size_t)(r0 + xrow) * EMB
                           : P + (size_t)(r0 - NQ + xrow) * EMB) + wg8;

    int arix = (lane & 15) * LST + (lane >> 4) * 8;
    int brix = (ht * 16 + (lane & 15)) * LST + (lane >> 4) * 8;

    floatx4 ac = {0, 0, 0, 0};
    float4 w00, w01, w10, w11, x0, x1;

    w00 = *(const float4*)&wp0[0]; w01 = *(const float4*)&wp0[4];
    w10 = *(const float4*)&wp1[0]; w11 = *(const float4*)&wp1[4];
    if (hasX) { x0 = *(const float4*)&xp[0]; x1 = *(const float4*)&xp[4]; }
    {
        short8 hi, lo;
        cvt8(w00, w01, hi, lo);
        *(short8*)&WH[0][wrow * LST + wg8] = hi;
        *(short8*)&WL[0][wrow * LST + wg8] = lo;
        cvt8(w10, w11, hi, lo);
        *(short8*)&WH[0][(wrow + 32) * LST + wg8] = hi;
        *(short8*)&WL[0][(wrow + 32) * LST + wg8] = lo;
        if (hasX) { short8 xh; cvt8hi(x0, x1, xh);
                    *(short8*)&XH[0][xrow * LST + wg8] = xh; }
    }

#pragma unroll 1
    for (int c = 0; c < 8; ++c) {
        int cur = c & 1;
        if (c < 7) {
            int k0 = (c + 1) * 64;
            w00 = *(const float4*)&wp0[k0]; w01 = *(const float4*)&wp0[k0 + 4];
            w10 = *(const float4*)&wp1[k0]; w11 = *(const float4*)&wp1[k0 + 4];
            if (hasX) { x0 = *(const float4*)&xp[k0]; x1 = *(const float4*)&xp[k0 + 4]; }
        }
        __syncthreads();

#pragma unroll
        for (int s = 0; s < 2; ++s) {
            short8 Ah = *(const short8*)&XH[cur][arix + s * 32];
            short8 Bh = *(const short8*)&WH[cur][brix + s * 32];
            short8 Bl = *(const short8*)&WL[cur][brix + s * 32];
            ac = __builtin_amdgcn_mfma_f32_16x16x32_bf16(Ah, Bl, ac, 0, 0, 0);
            ac = __builtin_amdgcn_mfma_f32_16x16x32_bf16(Ah, Bh, ac, 0, 0, 0);
        }

        if (c < 7) {
            int nb = cur ^ 1;
            short8 hi, lo;
            cvt8(w00, w01, hi, lo);
            *(short8*)&WH[nb][wrow * LST + wg8] = hi;
            *(short8*)&WL[nb][wrow * LST + wg8] = lo;
            cvt8(w10, w11, hi, lo);
            *(short8*)&WH[nb][(wrow + 32) * LST + wg8] = hi;
            *(short8*)&WL[nb][(wrow + 32) * LST + wg8] = lo;
            if (hasX) { short8 xh; cvt8hi(x0, x1, xh);
                        *(short8*)&XH[nb][xrow * LST + wg8] = xh; }
        }
    }

    int col  = lane & 15;
    int rloc = (lane >> 4) * 4;
    int hh   = ht * 16 + col;
    int rr   = r0 + rloc;

    if (isQ) {
        float bb = b1[m * 64 + hh];
        float* dst = &A[((size_t)m * NQ + rr) * HID + hh];
        dst[0 * HID] = ac.x + bb; dst[1 * HID] = ac.y + bb;
        dst[2 * HID] = ac.z + bb; dst[3 * HID] = ac.w + bb;
    } else {
        int p = rr - NQ;
        float* dst = &Bv[(((size_t)(m * 16 + (hh >> 2))) * NP + p) * 4 + (hh & 3)];
        dst[0 * 4] = ac.x; dst[1 * 4] = ac.y; dst[2 * 4] = ac.z; dst[3 * 4] = ac.w;
    }
}

// ---------------------------------------------------------------------------
// Kernel 2: fused relu-ensemble + mean/std/exp, v2.
// Key change: A/W2 are block-uniform, which the compiler routes through
// s_load batches + lgkmcnt drains (the R5/R6 gemmAB disease). An opaque
// lane offset (v_mov_b32 0 via asm) forces the vector path: uniform-address
// global_load_dwordx4 -> single L1 cacheline broadcast, no scalar serialization.
// 4 q/thread (512 blocks) halves B L2 re-read traffic vs 2q.
__global__ __launch_bounds__(256) void fused_v2(const float* __restrict__ A,
                                                const float* __restrict__ Bv,
                                                const float* __restrict__ W2,
                                                const float* __restrict__ b2,
                                                float* __restrict__ out) {
    int p  = threadIdx.x;            // 0..255
    int q0 = blockIdx.x * 4;

    int lz;                          // opaque 0 in a VGPR
    asm volatile("v_mov_b32 %0, 0" : "=v"(lz));
    const float* Az  = A + lz;       // lane-"varying" base -> vector loads
    const float* W2z = W2 + lz;

    float s10 = 0, s20 = 0, s11 = 0, s21 = 0;
    float s12 = 0, s22 = 0, s13 = 0, s23 = 0;
    const float4* Bq = (const float4*)Bv + p;

#pragma unroll 1
    for (int m = 0; m < NM; ++m) {
        const float4* bm = Bq + (size_t)m * 16 * NP;
        float4 B0 = bm[0*NP],  B1 = bm[1*NP],  B2 = bm[2*NP],  B3 = bm[3*NP];
        float4 B4 = bm[4*NP],  B5 = bm[5*NP],  B6 = bm[6*NP],  B7 = bm[7*NP];
        float4 B8 = bm[8*NP],  B9 = bm[9*NP],  B10= bm[10*NP], B11= bm[11*NP];
        float4 B12= bm[12*NP], B13= bm[13*NP], B14= bm[14*NP], B15= bm[15*NP];

        const float* Ar  = Az + ((size_t)m * NQ + q0) * HID;
        const float* Wp2 = W2z + m * HID;
        float o0 = 0.f, o1 = 0.f, o2 = 0.f, o3 = 0.f;

#define HSTEP(BF, H0) { \
        float4 wv = *(const float4*)&Wp2[H0]; \
        float4 a0 = *(const float4*)&Ar[H0]; \
        float4 a1 = *(const float4*)&Ar[64  + H0]; \
        float4 a2 = *(const float4*)&Ar[128 + H0]; \
        float4 a3 = *(const float4*)&Ar[192 + H0]; \
        o0 = fmaf(fmaxf(a0.x + BF.x, 0.f), wv.x, o0); \
        o0 = fmaf(fmaxf(a0.y + BF.y, 0.f), wv.y, o0); \
        o0 = fmaf(fmaxf(a0.z + BF.z, 0.f), wv.z, o0); \
        o0 = fmaf(fmaxf(a0.w + BF.w, 0.f), wv.w, o0); \
        o1 = fmaf(fmaxf(a1.x + BF.x, 0.f), wv.x, o1); \
        o1 = fmaf(fmaxf(a1.y + BF.y, 0.f), wv.y, o1); \
        o1 = fmaf(fmaxf(a1.z + BF.z, 0.f), wv.z, o1); \
        o1 = fmaf(fmaxf(a1.w + BF.w, 0.f), wv.w, o1); \
        o2 = fmaf(fmaxf(a2.x + BF.x, 0.f), wv.x, o2); \
        o2 = fmaf(fmaxf(a2.y + BF.y, 0.f), wv.y, o2); \
        o2 = fmaf(fmaxf(a2.z + BF.z, 0.f), wv.z, o2); \
        o2 = fmaf(fmaxf(a2.w + BF.w, 0.f), wv.w, o2); \
        o3 = fmaf(fmaxf(a3.x + BF.x, 0.f), wv.x, o3); \
        o3 = fmaf(fmaxf(a3.y + BF.y, 0.f), wv.y, o3); \
        o3 = fmaf(fmaxf(a3.z + BF.z, 0.f), wv.z, o3); \
        o3 = fmaf(fmaxf(a3.w + BF.w, 0.f), wv.w, o3); }

        HSTEP(B0,  0)  HSTEP(B1,  4)  HSTEP(B2,  8)  HSTEP(B3, 12)
        HSTEP(B4, 16)  HSTEP(B5, 20)  HSTEP(B6, 24)  HSTEP(B7, 28)
        HSTEP(B8, 32)  HSTEP(B9, 36)  HSTEP(B10,40)  HSTEP(B11,44)
        HSTEP(B12,48)  HSTEP(B13,52)  HSTEP(B14,56)  HSTEP(B15,60)
#undef HSTEP

        float bb = b2[m];
        float x0 = o0 + bb, x1 = o1 + bb, x2 = o2 + bb, x3 = o3 + bb;
        s10 += x0; s20 = fmaf(x0, x0, s20);
        s11 += x1; s21 = fmaf(x1, x1, s21);
        s12 += x2; s22 = fmaf(x2, x2, s22);
        s13 += x3; s23 = fmaf(x3, x3, s23);
    }

#define OUTW(J, S1, S2) { \
        float mean = S1 * 0.2f; \
        float var  = fmaxf((S2 - S1 * S1 * 0.2f) * 0.25f, 0.f); \
        out[(size_t)(q0 + J) * NP + p] = mean * __expf(-sqrtf(var)); }
    OUTW(0, s10, s20) OUTW(1, s11, s21) OUTW(2, s12, s22) OUTW(3, s13, s23)
#undef OUTW
}

// ---------------------------------------------------------------------------
extern "C" void kernel_launch(void* const* d_in, const int* in_sizes, int n_in,
                              void* d_out, int out_size, void* d_ws, size_t ws_size,
                              hipStream_t stream) {
    const float* Q  = (const float*)d_in[0];   // (2048, 512)
    const float* P  = (const float*)d_in[1];   // (256, 512)
    const float* W1 = (const float*)d_in[2];   // (5, 64, 1024)
    const float* b1 = (const float*)d_in[3];   // (5, 64)
    const float* W2 = (const float*)d_in[4];   // (5, 64)
    const float* b2 = (const float*)d_in[5];   // (5,)
    float* out = (float*)d_out;

    char*  ws = (char*)d_ws;
    float* A  = (float*)(ws + A_BY);
    float* B  = (float*)(ws + B_BY);

    gemm_v3<<<720, 256, 0, stream>>>(Q, P, W1, b1, A, B);
    fused_v2<<<512, 256, 0, stream>>>(A, B, W2, b2, out);
}

// Round 16
// 100.079 us; speedup vs baseline: 1.0504x; 1.0504x over previous
//
#include <hip/hip_runtime.h>
#include <math.h>

#define EMB 512
#define NM 5
#define HID 64
#define NQ 2048
#define NP 256

typedef __attribute__((ext_vector_type(8))) short short8;   // 8 bf16 = 16B
typedef __attribute__((ext_vector_type(4))) float floatx4;

// ws layout (bytes)
#define A_BY 0u                    // A[m][q][h] f32 (+b1)   2,621,440
#define B_BY 2621440u              // B[m][h/4][p][h%4] f32    327,680

#define LST 72                     // LDS row stride in shorts (144B, 16B-aligned)

__device__ inline unsigned short bfr(float f) {            // f32 -> bf16 RNE
    unsigned u = __float_as_uint(f);
    u += 0x7FFFu + ((u >> 16) & 1u);
    return (unsigned short)(u >> 16);
}

__device__ inline void cvt8(float4 a, float4 b, short8& hi, short8& lo) {
#define C1(I, V) { unsigned short h_ = bfr(V); hi[I] = (short)h_; \
    lo[I] = (short)bfr(V - __uint_as_float(((unsigned)h_) << 16)); }
    C1(0, a.x) C1(1, a.y) C1(2, a.z) C1(3, a.w)
    C1(4, b.x) C1(5, b.y) C1(6, b.z) C1(7, b.w)
#undef C1
}
__device__ inline void cvt8hi(float4 a, float4 b, short8& hi) {
    hi[0] = (short)bfr(a.x); hi[1] = (short)bfr(a.y);
    hi[2] = (short)bfr(a.z); hi[3] = (short)bfr(a.w);
    hi[4] = (short)bfr(b.x); hi[5] = (short)bfr(b.y);
    hi[6] = (short)bfr(b.z); hi[7] = (short)bfr(b.w);
}

// ---------------------------------------------------------------------------
// Kernel 1: WAVE-AUTONOMOUS MFMA GEMM — zero barriers.
// Grid 2880 = (m, rt, ht); block = 64 threads = 1 wave owning one 16x16 tile
// with private double-buffered LDS (13.5 KB). Within-wave LDS RAW/WAR is
// ordered by the in-order LDS pipe + backend lgkmcnt tracking — no s_barrier,
// so no vmcnt(0) drains: chunk c+1 global loads stay in flight across the
// MFMA block of chunk c. 2-term Ootomo split (Ah*Bl + Ah*Bh), absmax 9.8e-4.
__global__ __launch_bounds__(64) void gemm_w(const float* __restrict__ Q,
                                             const float* __restrict__ P,
                                             const float* __restrict__ W1,
                                             const float* __restrict__ b1,
                                             float* __restrict__ A,
                                             float* __restrict__ Bv) {
    __shared__ short XH[2][16 * LST];
    __shared__ short WH[2][16 * LST];
    __shared__ short WL[2][16 * LST];

    int lane = threadIdx.x;              // 0..63
    int b    = blockIdx.x;
    int ht   = b & 3;
    int mr   = b >> 2;
    int m    = mr % 5;
    int rt   = mr / 5;                   // 0..143
    int r0   = rt * 16;
    bool isQ = rt < 128;

    // staging: lane -> (row 0..15, 16-float k-segment)
    int srow = lane >> 2;                // 0..15
    int sk   = (lane & 3) * 16;          // float offset within 64-chunk
    const float* xp = (isQ ? Q + (size_t)(r0 + srow) * EMB
                           : P + (size_t)(r0 - NQ + srow) * EMB) + sk;
    const float* wp = W1 + ((size_t)m * 64 + ht * 16 + srow) * 1024
                      + (isQ ? 0 : EMB) + sk;

    int arix = (lane & 15) * LST + (lane >> 4) * 8;   // frag offset (A and B alike)

    floatx4 ac = {0, 0, 0, 0};
    float4 x0, x1, x2, x3, w0, w1, w2, w3;

    // prologue: load + convert + store chunk 0 into buf 0
    x0 = *(const float4*)&xp[0];  x1 = *(const float4*)&xp[4];
    x2 = *(const float4*)&xp[8];  x3 = *(const float4*)&xp[12];
    w0 = *(const float4*)&wp[0];  w1 = *(const float4*)&wp[4];
    w2 = *(const float4*)&wp[8];  w3 = *(const float4*)&wp[12];
    {
        short8 h0, h1, hi, lo;
        cvt8hi(x0, x1, h0); cvt8hi(x2, x3, h1);
        *(short8*)&XH[0][srow * LST + sk] = h0;
        *(short8*)&XH[0][srow * LST + sk + 8] = h1;
        cvt8(w0, w1, hi, lo);
        *(short8*)&WH[0][srow * LST + sk] = hi;
        *(short8*)&WL[0][srow * LST + sk] = lo;
        cvt8(w2, w3, hi, lo);
        *(short8*)&WH[0][srow * LST + sk + 8] = hi;
        *(short8*)&WL[0][srow * LST + sk + 8] = lo;
    }

#pragma unroll 1
    for (int c = 0; c < 8; ++c) {
        int cur = c & 1;
        if (c < 7) {                      // issue chunk c+1 loads (no wait)
            int k0 = (c + 1) * 64;
            x0 = *(const float4*)&xp[k0];     x1 = *(const float4*)&xp[k0 + 4];
            x2 = *(const float4*)&xp[k0 + 8]; x3 = *(const float4*)&xp[k0 + 12];
            w0 = *(const float4*)&wp[k0];     w1 = *(const float4*)&wp[k0 + 4];
            w2 = *(const float4*)&wp[k0 + 8]; w3 = *(const float4*)&wp[k0 + 12];
        }

#pragma unroll
        for (int s = 0; s < 2; ++s) {     // two 32-k sub-chunks
            short8 Ah = *(const short8*)&XH[cur][arix + s * 32];
            short8 Bh = *(const short8*)&WH[cur][arix + s * 32];
            short8 Bl = *(const short8*)&WL[cur][arix + s * 32];
            ac = __builtin_amdgcn_mfma_f32_16x16x32_bf16(Ah, Bl, ac, 0, 0, 0);
            ac = __builtin_amdgcn_mfma_f32_16x16x32_bf16(Ah, Bh, ac, 0, 0, 0);
        }

        if (c < 7) {                      // convert (vmcnt waits here) + store
            int nb = cur ^ 1;
            short8 h0, h1, hi, lo;
            cvt8hi(x0, x1, h0); cvt8hi(x2, x3, h1);
            *(short8*)&XH[nb][srow * LST + sk] = h0;
            *(short8*)&XH[nb][srow * LST + sk + 8] = h1;
            cvt8(w0, w1, hi, lo);
            *(short8*)&WH[nb][srow * LST + sk] = hi;
            *(short8*)&WL[nb][srow * LST + sk] = lo;
            cvt8(w2, w3, hi, lo);
            *(short8*)&WH[nb][srow * LST + sk + 8] = hi;
            *(short8*)&WL[nb][srow * LST + sk + 8] = lo;
        }
    }

    int col  = lane & 15;                 // h within tile
    int rloc = (lane >> 4) * 4;           // row within tile (+reg)
    int hh   = ht * 16 + col;
    int rr   = r0 + rloc;

    if (isQ) {
        float bb = b1[m * 64 + hh];
        float* dst = &A[((size_t)m * NQ + rr) * HID + hh];
        dst[0 * HID] = ac.x + bb; dst[1 * HID] = ac.y + bb;
        dst[2 * HID] = ac.z + bb; dst[3 * HID] = ac.w + bb;
    } else {
        int p = rr - NQ;
        float* dst = &Bv[(((size_t)(m * 16 + (hh >> 2))) * NP + p) * 4 + (hh & 3)];
        dst[0 * 4] = ac.x; dst[1 * 4] = ac.y; dst[2 * 4] = ac.z; dst[3 * 4] = ac.w;
    }
}

// ---------------------------------------------------------------------------
// Kernel 2: fused relu-ensemble + mean/std/exp — R14's exact kernel
// (2q/thread, 1024 blocks; best measured configuration).
__global__ __launch_bounds__(256) void fused_main(const float* __restrict__ A,
                                                  const float* __restrict__ Bv,
                                                  const float* __restrict__ W2,
                                                  const float* __restrict__ b2,
                                                  float* __restrict__ out) {
    int p  = threadIdx.x;            // 0..255
    int q0 = blockIdx.x * 2;

    float s1a = 0, s2a = 0, s1b = 0, s2b = 0;
    const float4* Bq = (const float4*)Bv + p;

#pragma unroll 1
    for (int m = 0; m < NM; ++m) {
        const float4* bm = Bq + (size_t)m * 16 * NP;
        float4 B0 = bm[0*NP],  B1 = bm[1*NP],  B2 = bm[2*NP],  B3 = bm[3*NP];
        float4 B4 = bm[4*NP],  B5 = bm[5*NP],  B6 = bm[6*NP],  B7 = bm[7*NP];
        float4 B8 = bm[8*NP],  B9 = bm[9*NP],  B10= bm[10*NP], B11= bm[11*NP];
        float4 B12= bm[12*NP], B13= bm[13*NP], B14= bm[14*NP], B15= bm[15*NP];

        const float* Ar  = A + ((size_t)m * NQ + q0) * HID;   // block-uniform
        const float* Wp2 = W2 + m * HID;                      // block-uniform
        float oa = 0.f, ob = 0.f;

#define HSTEP(BF, H0) { \
        float wa=Wp2[H0+0], wb=Wp2[H0+1], wc=Wp2[H0+2], wd=Wp2[H0+3]; \
        oa = fmaf(fmaxf(Ar[H0+0]    + BF.x, 0.f), wa, oa); \
        oa = fmaf(fmaxf(Ar[H0+1]    + BF.y, 0.f), wb, oa); \
        oa = fmaf(fmaxf(Ar[H0+2]    + BF.z, 0.f), wc, oa); \
        oa = fmaf(fmaxf(Ar[H0+3]    + BF.w, 0.f), wd, oa); \
        ob = fmaf(fmaxf(Ar[64+H0+0] + BF.x, 0.f), wa, ob); \
        ob = fmaf(fmaxf(Ar[64+H0+1] + BF.y, 0.f), wb, ob); \
        ob = fmaf(fmaxf(Ar[64+H0+2] + BF.z, 0.f), wc, ob); \
        ob = fmaf(fmaxf(Ar[64+H0+3] + BF.w, 0.f), wd, ob); }

        HSTEP(B0,  0)  HSTEP(B1,  4)  HSTEP(B2,  8)  HSTEP(B3, 12)
        HSTEP(B4, 16)  HSTEP(B5, 20)  HSTEP(B6, 24)  HSTEP(B7, 28)
        HSTEP(B8, 32)  HSTEP(B9, 36)  HSTEP(B10,40)  HSTEP(B11,44)
        HSTEP(B12,48)  HSTEP(B13,52)  HSTEP(B14,56)  HSTEP(B15,60)
#undef HSTEP

        float bb = b2[m];
        float xa = oa + bb, xb = ob + bb;
        s1a += xa; s2a = fmaf(xa, xa, s2a);
        s1b += xb; s2b = fmaf(xb, xb, s2b);
    }

    {
        float mean = s1a * 0.2f;
        float var  = fmaxf((s2a - s1a * s1a * 0.2f) * 0.25f, 0.f);
        out[(size_t)q0 * NP + p] = mean * __expf(-sqrtf(var));
    }
    {
        float mean = s1b * 0.2f;
        float var  = fmaxf((s2b - s1b * s1b * 0.2f) * 0.25f, 0.f);
        out[(size_t)(q0 + 1) * NP + p] = mean * __expf(-sqrtf(var));
    }
}

// ---------------------------------------------------------------------------
extern "C" void kernel_launch(void* const* d_in, const int* in_sizes, int n_in,
                              void* d_out, int out_size, void* d_ws, size_t ws_size,
                              hipStream_t stream) {
    const float* Q  = (const float*)d_in[0];   // (2048, 512)
    const float* P  = (const float*)d_in[1];   // (256, 512)
    const float* W1 = (const float*)d_in[2];   // (5, 64, 1024)
    const float* b1 = (const float*)d_in[3];   // (5, 64)
    const float* W2 = (const float*)d_in[4];   // (5, 64)
    const float* b2 = (const float*)d_in[5];   // (5,)
    float* out = (float*)d_out;

    char*  ws = (char*)d_ws;
    float* A  = (float*)(ws + A_BY);
    float* B  = (float*)(ws + B_BY);

    gemm_w<<<2880, 64, 0, stream>>>(Q, P, W1, b1, A, B);
    fused_main<<<1024, 256, 0, stream>>>(A, B, W2, b2, out);
}

// Round 17
// 93.162 us; speedup vs baseline: 1.1284x; 1.0742x over previous
//
#include <hip/hip_runtime.h>
#include <math.h>

#define EMB 512
#define NM 5
#define HID 64
#define NQ 2048
#define NP 256

typedef __attribute__((ext_vector_type(8))) short short8;   // 8 bf16 = 16B
typedef __attribute__((ext_vector_type(4))) float floatx4;

// ws layout (bytes)
#define A_BY 0u                    // A[m][q][h] f32 (+b1)   2,621,440
#define B_BY 2621440u              // B[m][h/4][p][h%4] f32    327,680

#define LST 72                     // LDS row stride in shorts (144B, 16B-aligned)

__device__ inline unsigned short bfr(float f) {            // f32 -> bf16 RNE
    unsigned u = __float_as_uint(f);
    u += 0x7FFFu + ((u >> 16) & 1u);
    return (unsigned short)(u >> 16);
}

__device__ inline void cvt8(float4 a, float4 b, short8& hi, short8& lo) {
#define C1(I, V) { unsigned short h_ = bfr(V); hi[I] = (short)h_; \
    lo[I] = (short)bfr(V - __uint_as_float(((unsigned)h_) << 16)); }
    C1(0, a.x) C1(1, a.y) C1(2, a.z) C1(3, a.w)
    C1(4, b.x) C1(5, b.y) C1(6, b.z) C1(7, b.w)
#undef C1
}
__device__ inline void cvt8hi(float4 a, float4 b, short8& hi) {
    hi[0] = (short)bfr(a.x); hi[1] = (short)bfr(a.y);
    hi[2] = (short)bfr(a.z); hi[3] = (short)bfr(a.w);
    hi[4] = (short)bfr(b.x); hi[5] = (short)bfr(b.y);
    hi[6] = (short)bfr(b.z); hi[7] = (short)bfr(b.w);
}

// ---------------------------------------------------------------------------
// Kernel 1: LDS double-buffered MFMA GEMM — ONE barrier per 64-K chunk.
// Grid 720 = (m, rt of 16 rows); block = 4 waves = 4 h-tiles of 16.
// X staged once per block (shared by 4 waves); W 64 rows staged cooperatively
// (hi+lo 2-term Ootomo split: Ah*Bl + Ah*Bh, measured absmax 9.8e-4).
// Chunk c+1 loads issue before the barrier+MFMA of chunk c (vmcnt covered).
// Best-measured GEMM configuration (R14, total 92.6 us).
__global__ __launch_bounds__(256) void gemm_v3(const float* __restrict__ Q,
                                               const float* __restrict__ P,
                                               const float* __restrict__ W1,
                                               const float* __restrict__ b1,
                                               float* __restrict__ A,
                                               float* __restrict__ Bv) {
    __shared__ short XH[2][16 * LST];
    __shared__ short WH[2][64 * LST];
    __shared__ short WL[2][64 * LST];

    int tid  = threadIdx.x;
    int lane = tid & 63;
    int ht   = tid >> 6;
    int m    = blockIdx.x % 5;
    int rt   = blockIdx.x / 5;           // 0..143
    int r0   = rt * 16;
    bool isQ = rt < 128;

    int wrow = tid >> 3;                 // 0..31  (also rows +32)
    int wg8  = (tid & 7) * 8;            // k offset within 64-chunk
    const float* wb  = W1 + (size_t)m * 64 * 1024 + (isQ ? 0 : EMB);
    const float* wp0 = wb + (size_t)wrow * 1024 + wg8;
    const float* wp1 = wb + (size_t)(wrow + 32) * 1024 + wg8;
    bool hasX = tid < 128;
    int xrow  = tid >> 3;                // 0..15 when hasX
    const float* xp = (isQ ? Q + (size_t)(r0 + xrow) * EMB
                           : P + (size_t)(r0 - NQ + xrow) * EMB) + wg8;

    int arix = (lane & 15) * LST + (lane >> 4) * 8;
    int brix = (ht * 16 + (lane & 15)) * LST + (lane >> 4) * 8;

    floatx4 ac = {0, 0, 0, 0};
    float4 w00, w01, w10, w11, x0, x1;

    w00 = *(const float4*)&wp0[0]; w01 = *(const float4*)&wp0[4];
    w10 = *(const float4*)&wp1[0]; w11 = *(const float4*)&wp1[4];
    if (hasX) { x0 = *(const float4*)&xp[0]; x1 = *(const float4*)&xp[4]; }
    {
        short8 hi, lo;
        cvt8(w00, w01, hi, lo);
        *(short8*)&WH[0][wrow * LST + wg8] = hi;
        *(short8*)&WL[0][wrow * LST + wg8] = lo;
        cvt8(w10, w11, hi, lo);
        *(short8*)&WH[0][(wrow + 32) * LST + wg8] = hi;
        *(short8*)&WL[0][(wrow + 32) * LST + wg8] = lo;
        if (hasX) { short8 xh; cvt8hi(x0, x1, xh);
                    *(short8*)&XH[0][xrow * LST + wg8] = xh; }
    }

#pragma unroll 1
    for (int c = 0; c < 8; ++c) {
        int cur = c & 1;
        if (c < 7) {
            int k0 = (c + 1) * 64;
            w00 = *(const float4*)&wp0[k0]; w01 = *(const float4*)&wp0[k0 + 4];
            w10 = *(const float4*)&wp1[k0]; w11 = *(const float4*)&wp1[k0 + 4];
            if (hasX) { x0 = *(const float4*)&xp[k0]; x1 = *(const float4*)&xp[k0 + 4]; }
        }
        __syncthreads();

#pragma unroll
        for (int s = 0; s < 2; ++s) {
            short8 Ah = *(const short8*)&XH[cur][arix + s * 32];
            short8 Bh = *(const short8*)&WH[cur][brix + s * 32];
            short8 Bl = *(const short8*)&WL[cur][brix + s * 32];
            ac = __builtin_amdgcn_mfma_f32_16x16x32_bf16(Ah, Bl, ac, 0, 0, 0);
            ac = __builtin_amdgcn_mfma_f32_16x16x32_bf16(Ah, Bh, ac, 0, 0, 0);
        }

        if (c < 7) {
            int nb = cur ^ 1;
            short8 hi, lo;
            cvt8(w00, w01, hi, lo);
            *(short8*)&WH[nb][wrow * LST + wg8] = hi;
            *(short8*)&WL[nb][wrow * LST + wg8] = lo;
            cvt8(w10, w11, hi, lo);
            *(short8*)&WH[nb][(wrow + 32) * LST + wg8] = hi;
            *(short8*)&WL[nb][(wrow + 32) * LST + wg8] = lo;
            if (hasX) { short8 xh; cvt8hi(x0, x1, xh);
                        *(short8*)&XH[nb][xrow * LST + wg8] = xh; }
        }
    }

    int col  = lane & 15;
    int rloc = (lane >> 4) * 4;
    int hh   = ht * 16 + col;
    int rr   = r0 + rloc;

    if (isQ) {
        float bb = b1[m * 64 + hh];
        float* dst = &A[((size_t)m * NQ + rr) * HID + hh];
        dst[0 * HID] = ac.x + bb; dst[1 * HID] = ac.y + bb;
        dst[2 * HID] = ac.z + bb; dst[3 * HID] = ac.w + bb;
    } else {
        int p = rr - NQ;
        float* dst = &Bv[(((size_t)(m * 16 + (hh >> 2))) * NP + p) * 4 + (hh & 3)];
        dst[0 * 4] = ac.x; dst[1 * 4] = ac.y; dst[2 * 4] = ac.z; dst[3 * 4] = ac.w;
    }
}

// ---------------------------------------------------------------------------
// Kernel 2: fused relu-ensemble + mean/std/exp — 2q/thread, 1024 blocks
// (best measured configuration: 4q/512-blk regressed twice; vector-broadcast
// A-path regressed; block-uniform s_load A/W2 is the fastest variant).
__global__ __launch_bounds__(256) void fused_main(const float* __restrict__ A,
                                                  const float* __restrict__ Bv,
                                                  const float* __restrict__ W2,
                                                  const float* __restrict__ b2,
                                                  float* __restrict__ out) {
    int p  = threadIdx.x;            // 0..255
    int q0 = blockIdx.x * 2;

    float s1a = 0, s2a = 0, s1b = 0, s2b = 0;
    const float4* Bq = (const float4*)Bv + p;

#pragma unroll 1
    for (int m = 0; m < NM; ++m) {
        const float4* bm = Bq + (size_t)m * 16 * NP;
        float4 B0 = bm[0*NP],  B1 = bm[1*NP],  B2 = bm[2*NP],  B3 = bm[3*NP];
        float4 B4 = bm[4*NP],  B5 = bm[5*NP],  B6 = bm[6*NP],  B7 = bm[7*NP];
        float4 B8 = bm[8*NP],  B9 = bm[9*NP],  B10= bm[10*NP], B11= bm[11*NP];
        float4 B12= bm[12*NP], B13= bm[13*NP], B14= bm[14*NP], B15= bm[15*NP];

        const float* Ar  = A + ((size_t)m * NQ + q0) * HID;   // block-uniform
        const float* Wp2 = W2 + m * HID;                      // block-uniform
        float oa = 0.f, ob = 0.f;

#define HSTEP(BF, H0) { \
        float wa=Wp2[H0+0], wb=Wp2[H0+1], wc=Wp2[H0+2], wd=Wp2[H0+3]; \
        oa = fmaf(fmaxf(Ar[H0+0]    + BF.x, 0.f), wa, oa); \
        oa = fmaf(fmaxf(Ar[H0+1]    + BF.y, 0.f), wb, oa); \
        oa = fmaf(fmaxf(Ar[H0+2]    + BF.z, 0.f), wc, oa); \
        oa = fmaf(fmaxf(Ar[H0+3]    + BF.w, 0.f), wd, oa); \
        ob = fmaf(fmaxf(Ar[64+H0+0] + BF.x, 0.f), wa, ob); \
        ob = fmaf(fmaxf(Ar[64+H0+1] + BF.y, 0.f), wb, ob); \
        ob = fmaf(fmaxf(Ar[64+H0+2] + BF.z, 0.f), wc, ob); \
        ob = fmaf(fmaxf(Ar[64+H0+3] + BF.w, 0.f), wd, ob); }

        HSTEP(B0,  0)  HSTEP(B1,  4)  HSTEP(B2,  8)  HSTEP(B3, 12)
        HSTEP(B4, 16)  HSTEP(B5, 20)  HSTEP(B6, 24)  HSTEP(B7, 28)
        HSTEP(B8, 32)  HSTEP(B9, 36)  HSTEP(B10,40)  HSTEP(B11,44)
        HSTEP(B12,48)  HSTEP(B13,52)  HSTEP(B14,56)  HSTEP(B15,60)
#undef HSTEP

        float bb = b2[m];
        float xa = oa + bb, xb = ob + bb;
        s1a += xa; s2a = fmaf(xa, xa, s2a);
        s1b += xb; s2b = fmaf(xb, xb, s2b);
    }

    {
        float mean = s1a * 0.2f;
        float var  = fmaxf((s2a - s1a * s1a * 0.2f) * 0.25f, 0.f);
        out[(size_t)q0 * NP + p] = mean * __expf(-sqrtf(var));
    }
    {
        float mean = s1b * 0.2f;
        float var  = fmaxf((s2b - s1b * s1b * 0.2f) * 0.25f, 0.f);
        out[(size_t)(q0 + 1) * NP + p] = mean * __expf(-sqrtf(var));
    }
}

// ---------------------------------------------------------------------------
extern "C" void kernel_launch(void* const* d_in, const int* in_sizes, int n_in,
                              void* d_out, int out_size, void* d_ws, size_t ws_size,
                              hipStream_t stream) {
    const float* Q  = (const float*)d_in[0];   // (2048, 512)
    const float* P  = (const float*)d_in[1];   // (256, 512)
    const float* W1 = (const float*)d_in[2];   // (5, 64, 1024)
    const float* b1 = (const float*)d_in[3];   // (5, 64)
    const float* W2 = (const float*)d_in[4];   // (5, 64)
    const float* b2 = (const float*)d_in[5];   // (5,)
    float* out = (float*)d_out;

    char*  ws = (char*)d_ws;
    float* A  = (float*)(ws + A_BY);
    float* B  = (float*)(ws + B_BY);

    gemm_v3<<<720, 256, 0, stream>>>(Q, P, W1, b1, A, B);
    fused_main<<<1024, 256, 0, stream>>>(A, B, W2, b2, out);
}